// Round 1
// baseline (638.397 us; speedup 1.0000x reference)
//
#include <hip/hip_runtime.h>
#include <hip/hip_bf16.h>
#include <math.h>

#define GS 1024
#define BSZ 256
#define DD 128
#define NEGV -1e30f

typedef __attribute__((ext_vector_type(8))) short bf16x8_t;
typedef __attribute__((ext_vector_type(4))) float f32x4_t;

// ---- workspace layout ----
// bytes [0, 131072): W_K1..4 as bf16 [mat][d][k]
#define WBF_BYTES (65536 * 2)
// float region F starts at WBF_BYTES; offsets in floats:
#define FA_WQT   0         // 4*16384  [mat][k][d], mat order Q1,Q2,Q3,Q4
#define FB_IHWT  65536     // 16384    [k][d]
#define FC_R1IH  81920     // 49152    [gate][k][d]
#define FD_R1HH  131072    // 49152
#define FE_R2IH  180224    // 49152
#define FG_R2HH  229376    // 49152
#define FH_HM    278528    // 256*8*128 h-mean partials [b][seg][d]
#define FI_V     540672    // 256*256  [b][256] (V1|V2)
#define FJ_AQB   606208    // 256*4*4*128 [b][j][{a1,b1,a2,b2}][d]
#define FK_RES   868352    // 256*1024*4 [b][g][j]
#define F_TOTAL  (868352 + 4194304)
#define DESC_OFF_BYTES (WBF_BYTES + F_TOTAL * 4)   // int [b][32]

__device__ __forceinline__ float fast_tanh(float x) {
    float ax = fabsf(x);
    float e  = __expf(2.0f * ax);
    float t  = 1.0f - 2.0f / (e + 1.0f);
    return (x >= 0.0f) ? t : -t;
}
__device__ __forceinline__ float sigm(float x) { return 1.0f / (1.0f + __expf(-x)); }
__device__ __forceinline__ unsigned short f2bf(float f) {
    union { float f; unsigned u; } v; v.f = f;
    unsigned u = v.u;
    return (unsigned short)((u + 0x7fffu + ((u >> 16) & 1u)) >> 16);
}

// ---------------- kernel 1: pack / transpose weights ----------------
__global__ __launch_bounds__(256) void pack_kernel(
    const float* __restrict__ wk1, const float* __restrict__ wk2,
    const float* __restrict__ wk3, const float* __restrict__ wk4,
    const float* __restrict__ wq1, const float* __restrict__ wq2,
    const float* __restrict__ wq3, const float* __restrict__ wq4,
    const float* __restrict__ ihw,
    const float* __restrict__ r1ih, const float* __restrict__ r1hh,
    const float* __restrict__ r2ih, const float* __restrict__ r2hh,
    unsigned short* __restrict__ wbf, float* __restrict__ F)
{
    int tid = blockIdx.x * blockDim.x + threadIdx.x;
    int nth = gridDim.x * blockDim.x;
    const float* wks[4] = {wk1, wk2, wk3, wk4};
    const float* wqs[4] = {wq1, wq2, wq3, wq4};
    const float* rws[4] = {r1ih, r1hh, r2ih, r2hh};
    const int    rbs[4] = {FC_R1IH, FD_R1HH, FE_R2IH, FG_R2HH};

    for (int e = tid; e < 65536; e += nth) {           // bf16 W_K, same layout [d][k]
        int mat = e >> 14;
        wbf[e] = f2bf(wks[mat][e & 16383]);
    }
    for (int e = tid; e < 65536; e += nth) {           // W_Q transposed [mat][k][d]
        int mat = e >> 14, k = (e >> 7) & 127, d = e & 127;
        F[FA_WQT + e] = wqs[mat][d * 128 + k];
    }
    for (int e = tid; e < 16384; e += nth) {           // init_hidden_W transposed
        int k = e >> 7, d = e & 127;
        F[FB_IHWT + e] = ihw[d * 128 + k];
    }
    for (int m = 0; m < 4; m++) {                      // GRU weights [gate][k][d]
        const float* src = rws[m];
        float* dst = F + rbs[m];
        for (int e = tid; e < 49152; e += nth) {
            int g = e >> 14, k = (e >> 7) & 127, d = e & 127;
            dst[e] = src[(g * 128 + d) * 128 + k];
        }
    }
}

// ---------------- kernel 2: h-mean partial sums ----------------
__global__ __launch_bounds__(128) void hmean_kernel(const float* __restrict__ h,
                                                    float* __restrict__ F)
{
    int b = blockIdx.x >> 3, seg = blockIdx.x & 7, d = threadIdx.x;
    const float* base = h + ((size_t)(b * GS + seg * 128)) * DD + d;
    float s = 0.0f;
#pragma unroll 8
    for (int r = 0; r < 128; r++) s += base[(size_t)r * DD];
    F[FH_HM + b * 1024 + seg * 128 + d] = s;
}

// ---------------- GRU step helper (all 128 threads) ----------------
__device__ void gru_step(float* qs, const float* xs,
                         const float* __restrict__ Wiht, const float* __restrict__ Whht,
                         const float* __restrict__ bih, const float* __restrict__ bhh,
                         int tid)
{
    float xr = bih[tid], xz = bih[tid + 128], xn = bih[tid + 256];
    float hr = bhh[tid], hz = bhh[tid + 128], hn = bhh[tid + 256];
    for (int k = 0; k < 128; k++) {
        float xv = xs[k], hv = qs[k];
        xr += Wiht[k * 128 + tid] * xv;
        xz += Wiht[16384 + k * 128 + tid] * xv;
        xn += Wiht[32768 + k * 128 + tid] * xv;
        hr += Whht[k * 128 + tid] * hv;
        hz += Whht[16384 + k * 128 + tid] * hv;
        hn += Whht[32768 + k * 128 + tid] * hv;
    }
    float r = sigm(xr + hr), z = sigm(xz + hz);
    float n = fast_tanh(xn + r * hn);
    float nq = (1.0f - z) * n + z * qs[tid];
    __syncthreads();
    qs[tid] = nq;
    __syncthreads();
}

// ---------------- kernel 3: per-batch prep (meta, int machine, GRUs, a/b vecs) ---
__global__ __launch_bounds__(128) void prep_kernel(
    const float* __restrict__ h, const float* __restrict__ ctx2,
    const int* __restrict__ rec, const int* __restrict__ vt,
    const int* __restrict__ la_, const int* __restrict__ fa,
    const float* __restrict__ mW1, const float* __restrict__ mb1,
    const float* __restrict__ mW2, const float* __restrict__ mb2,
    const float* __restrict__ ihb, const float* __restrict__ iq,
    const float* __restrict__ b1ih, const float* __restrict__ b1hh,
    const float* __restrict__ b2ih, const float* __restrict__ b2hh,
    float* __restrict__ F, int* __restrict__ DESC, float* __restrict__ out)
{
    int b = blockIdx.x, tid = threadIdx.x;
    __shared__ float hm[128], q1s[128], q2s[128], x1s[128], x2s[128], hid8[8], c2s[9];
    __shared__ int idesc[32];

    float s = 0.0f;
#pragma unroll
    for (int seg = 0; seg < 8; seg++) s += F[FH_HM + b * 1024 + seg * 128 + tid];
    hm[tid] = s * (1.0f / 1024.0f);
    if (tid < 9) c2s[tid] = ctx2[b * 9 + tid];

    if (tid == 0) {
        // exact integer state machine (matches jax loop order)
        int ai[4], kal[5] = {0, 0, 0, 0, 0}, kar[4] = {0, 0, 0, 0};
        int stopped = 1, nola = -1, vt0 = 0;
        for (int i = 0; i < 4; i++) {
            idesc[16 + i] = stopped;   // s_enter
            idesc[22 + i] = nola;      // nola_enter
            int action = fa[b * 4 + i];
            if (i > 0 && stopped) action = ai[0];
            int nona = rec[b * GS + action];
            ai[i] = action;
            if (stopped) kal[i] = action;
            int jprev = (i + 3) & 3;
            if (!stopped) kar[jprev] = action;
            kal[i + 1] = nona;
            int hit = (action == nola) ? 1 : 0;
            int st = (i > 0) ? (stopped | hit) : hit;
            if (st) kal[i] = kal[(i + 4) % 5];
            if (st) kar[i] = kar[jprev];
            if (i == 0) vt0 = vt[b * GS + action];
            idesc[0 + i]  = action;
            idesc[4 + i]  = (vt[b * GS + action] - vt0) & (GS - 1);  // vtt at action
            idesc[8 + i]  = st;                                       // st_after
            idesc[12 + i] = (!st && (nona == ai[0])) ? 1 : 0;         // allow
            nola = st ? -1 : nona;
            stopped = st;
        }
        if (!stopped) kar[3] = kal[4];
        idesc[20] = la_[b];
        idesc[21] = vt0;
        int* dd = DESC + b * 32;
        for (int c = 0; c < 32; c++) dd[c] = (c < 26) ? idesc[c] : 0;
        float* oa = out + b * 12;
        for (int c = 0; c < 4; c++) {
            oa[c]     = (float)ai[c];
            oa[4 + c] = (float)kal[c];
            oa[8 + c] = (float)kar[c];
        }
    }
    __syncthreads();

    if (tid < 8) {
        float a = mb1[tid];
        for (int k = 0; k < 9; k++) a += mW1[tid * 9 + k] * c2s[k];
        hid8[tid] = a > 0.0f ? a : 0.0f;
    }
    __syncthreads();
    {   // V1 | V2
        float a = mb2[tid], c = mb2[tid + 128];
        for (int k = 0; k < 8; k++) {
            float hv = hid8[k];
            a += mW2[tid * 8 + k] * hv;
            c += mW2[(tid + 128) * 8 + k] * hv;
        }
        F[FI_V + b * 256 + tid] = a;
        F[FI_V + b * 256 + 128 + tid] = c;
    }
    {   // q0 = IHW @ h_mean + b
        float q = ihb[tid];
        for (int k = 0; k < 128; k++) q += F[FB_IHWT + k * 128 + tid] * hm[k];
        q1s[tid] = q; q2s[tid] = q;
    }
    x1s[tid] = iq[tid]; x2s[tid] = iq[tid];
    __syncthreads();

    for (int i = 0; i < 4; i++) {
        gru_step(q1s, x1s, F + FC_R1IH, F + FD_R1HH, b1ih, b1hh, tid);
        gru_step(q2s, x2s, F + FE_R2IH, F + FG_R2HH, b2ih, b2hh, tid);
        float a1 = 0.f, bq1 = 0.f, a2 = 0.f, bq2 = 0.f;
        for (int k = 0; k < 128; k++) {
            float q1v = q1s[k], q2v = q2s[k];
            a1  += F[FA_WQT + 0 * 16384 + k * 128 + tid] * q1v;  // Q1
            bq1 += F[FA_WQT + 2 * 16384 + k * 128 + tid] * q1v;  // Q3
            a2  += F[FA_WQT + 1 * 16384 + k * 128 + tid] * q2v;  // Q2
            bq2 += F[FA_WQT + 3 * 16384 + k * 128 + tid] * q2v;  // Q4
        }
        float* aq = F + FJ_AQB + b * 2048 + i * 512;
        aq[0 * 128 + tid] = a1;
        aq[1 * 128 + tid] = bq1;
        aq[2 * 128 + tid] = a2;
        aq[3 * 128 + tid] = bq2;
        if (i < 3) {
            int a_i = idesc[0 + i], sE = idesc[16 + i], nl = idesc[22 + i];
            float xv1 = h[((size_t)(b * GS + a_i)) * DD + tid];
            float xv2 = sE ? xv1 : h[((size_t)(b * GS + (nl & (GS - 1)))) * DD + tid];
            __syncthreads();
            x1s[tid] = xv1; x2s[tid] = xv2;
            __syncthreads();
        }
    }
}

// ---------------- kernel 4: fused MFMA score kernel ----------------
// wave = one 16-g tile; K1..K4 via mfma_f32_16x16x32_bf16 (A = h rows, B = W_K^T),
// immediately consumed by tanh-combine, reduced over d into RES[b][g][j].
__global__ __launch_bounds__(256) void score_kernel(
    const float* __restrict__ h, const unsigned short* __restrict__ wbf,
    float* __restrict__ F)
{
    int lane = threadIdx.x & 63, w = threadIdx.x >> 6;
    int b  = blockIdx.x >> 4;
    int gt = ((blockIdx.x & 15) << 2) | w;
    int g0 = gt << 4;
    int m = lane & 15, quad = lane >> 4;

    // A-fragments: A[m=lane&15][k = kt*32 + quad*8 + j], resident for whole wave
    bf16x8_t af[4];
    const float* hrow = h + ((size_t)(b * GS + g0 + m)) * DD + quad * 8;
#pragma unroll
    for (int kt = 0; kt < 4; kt++) {
        f32x4_t f0 = *(const f32x4_t*)(hrow + kt * 32);
        f32x4_t f1 = *(const f32x4_t*)(hrow + kt * 32 + 4);
        bf16x8_t a;
        a[0] = (short)f2bf(f0[0]); a[1] = (short)f2bf(f0[1]);
        a[2] = (short)f2bf(f0[2]); a[3] = (short)f2bf(f0[3]);
        a[4] = (short)f2bf(f1[0]); a[5] = (short)f2bf(f1[1]);
        a[6] = (short)f2bf(f1[2]); a[7] = (short)f2bf(f1[3]);
        af[kt] = a;
    }

    float accp[4][4];
#pragma unroll
    for (int r = 0; r < 4; r++)
#pragma unroll
        for (int j = 0; j < 4; j++) accp[r][j] = 0.0f;

    const float* Vb = F + FI_V + b * 256;
    const float* AQ = F + FJ_AQB + b * 2048;

    for (int nt = 0; nt < 8; nt++) {
        int dg = nt * 16 + m;
        f32x4_t c[4];
#pragma unroll
        for (int mat = 0; mat < 4; mat++) {
            f32x4_t acc = {0.f, 0.f, 0.f, 0.f};
            const unsigned short* wb = wbf + (mat * 128 + dg) * 128 + quad * 8;
#pragma unroll
            for (int kt = 0; kt < 4; kt++) {
                bf16x8_t bfr = *(const bf16x8_t*)(wb + kt * 32);
                acc = __builtin_amdgcn_mfma_f32_16x16x32_bf16(af[kt], bfr, acc, 0, 0, 0);
            }
            c[mat] = acc;
        }
        float V1d = Vb[dg], V2d = Vb[128 + dg];
#pragma unroll
        for (int j = 0; j < 4; j++) {
            float a1 = AQ[j * 512 + 0 * 128 + dg];
            float b1 = AQ[j * 512 + 1 * 128 + dg];
            float a2 = AQ[j * 512 + 2 * 128 + dg];
            float b2 = AQ[j * 512 + 3 * 128 + dg];
#pragma unroll
            for (int r = 0; r < 4; r++) {
                // C/D layout: row g = g0 + quad*4 + r, col d = dg
                float t1 = fast_tanh(c[0][r] + a1 + c[2][r] * b1);
                float t2 = fast_tanh(c[1][r] + a2 + c[3][r] * b2);
                accp[r][j] += t1 * V1d + t2 * V2d;
            }
        }
    }
    // reduce over the 16 d-lanes of each quad group
#pragma unroll
    for (int r = 0; r < 4; r++)
#pragma unroll
        for (int j = 0; j < 4; j++) {
            float v = accp[r][j];
            v += __shfl_xor(v, 1);
            v += __shfl_xor(v, 2);
            v += __shfl_xor(v, 4);
            v += __shfl_xor(v, 8);
            accp[r][j] = v;
        }
    int rr = m >> 2, jj = m & 3;
    float outv = 0.0f;
#pragma unroll
    for (int r = 0; r < 4; r++)
#pragma unroll
        for (int j = 0; j < 4; j++)
            if (rr == r && jj == j) outv = accp[r][j];
    F[FK_RES + ((size_t)(b * GS) + g0 + quad * 4 + rr) * 4 + jj] = outv;
}

// ---------------- kernel 5: masked log-softmax + ll ----------------
__global__ __launch_bounds__(256) void finalize_kernel(
    const float* __restrict__ F, const int* __restrict__ DESC,
    const int* __restrict__ vt, float* __restrict__ out)
{
    int b = blockIdx.x, t = threadIdx.x;
    const int* dd = DESC + b * 32;
    int act0 = dd[0], la = dd[20], vt0 = dd[21];
    __shared__ float sred[8];
    __shared__ float schosen;
    float ll = 0.0f;

    int vtts[4];
#pragma unroll
    for (int q = 0; q < 4; q++) {
        int g = t + q * 256;
        vtts[q] = (vt[b * GS + g] - vt0) & (GS - 1);
    }

    for (int j = 0; j < 4; j++) {
        int aj = dd[j];
        float lg[4];
#pragma unroll
        for (int q = 0; q < 4; q++) {
            int g = t + q * 256;
            bool neg;
            if (j == 0) {
                neg = (g == la);
            } else {
                int p = j - 1;
                neg = (vtts[q] <= dd[4 + p]) || (p == 0 && vtts[q] > GS - 2);
                if (dd[8 + p] && g == dd[p]) neg = false;       // stopped clear at act[p]
                if (dd[12 + p] && g == act0) neg = false;       // allow clear at act0
            }
            float r = F[FK_RES + ((size_t)(b * GS) + g) * 4 + j];
            float v = neg ? NEGV : 6.0f * fast_tanh(r);
            lg[q] = v;
            if (g == aj) schosen = v;
        }
        float mx = fmaxf(fmaxf(lg[0], lg[1]), fmaxf(lg[2], lg[3]));
#pragma unroll
        for (int o = 1; o < 64; o <<= 1) mx = fmaxf(mx, __shfl_xor(mx, o));
        if ((t & 63) == 0) sred[t >> 6] = mx;
        __syncthreads();
        mx = fmaxf(fmaxf(sred[0], sred[1]), fmaxf(sred[2], sred[3]));
        float sm = 0.0f;
#pragma unroll
        for (int q = 0; q < 4; q++) sm += __expf(lg[q] - mx);
#pragma unroll
        for (int o = 1; o < 64; o <<= 1) sm += __shfl_xor(sm, o);
        if ((t & 63) == 0) sred[4 + (t >> 6)] = sm;
        __syncthreads();
        if (t == 0) {
            float tot = sred[4] + sred[5] + sred[6] + sred[7];
            float lse = mx + logf(tot);
            int gate = (j == 0) || (!dd[16 + j]);   // i==0 always; else !s_enter
            if (gate) ll += schosen - lse;
        }
        __syncthreads();
    }
    if (t == 0) out[3072 + b] = ll;
}

extern "C" void kernel_launch(void* const* d_in, const int* in_sizes, int n_in,
                              void* d_out, int out_size, void* d_ws, size_t ws_size,
                              hipStream_t stream)
{
    (void)in_sizes; (void)n_in; (void)out_size; (void)ws_size;
    const float* h    = (const float*)d_in[0];
    const float* ctx2 = (const float*)d_in[1];
    const int*   rec  = (const int*)d_in[2];
    const int*   vtm  = (const int*)d_in[3];
    const int*   la   = (const int*)d_in[4];
    const int*   fa   = (const int*)d_in[5];
    const float* wk1 = (const float*)d_in[7];
    const float* wk2 = (const float*)d_in[8];
    const float* wk3 = (const float*)d_in[9];
    const float* wk4 = (const float*)d_in[10];
    const float* wq1 = (const float*)d_in[11];
    const float* wq2 = (const float*)d_in[12];
    const float* wq3 = (const float*)d_in[13];
    const float* wq4 = (const float*)d_in[14];
    const float* mW1 = (const float*)d_in[15];
    const float* mb1 = (const float*)d_in[16];
    const float* mW2 = (const float*)d_in[17];
    const float* mb2 = (const float*)d_in[18];
    const float* ihw = (const float*)d_in[19];
    const float* ihb = (const float*)d_in[20];
    const float* iq  = (const float*)d_in[21];
    const float* r1ih = (const float*)d_in[22];
    const float* r1hh = (const float*)d_in[23];
    const float* b1ih = (const float*)d_in[24];
    const float* b1hh = (const float*)d_in[25];
    const float* r2ih = (const float*)d_in[26];
    const float* r2hh = (const float*)d_in[27];
    const float* b2ih = (const float*)d_in[28];
    const float* b2hh = (const float*)d_in[29];

    unsigned short* wbf = (unsigned short*)d_ws;
    float* F   = (float*)((char*)d_ws + WBF_BYTES);
    int* DESC  = (int*)((char*)d_ws + DESC_OFF_BYTES);
    float* out = (float*)d_out;

    pack_kernel<<<dim3(256), dim3(256), 0, stream>>>(wk1, wk2, wk3, wk4,
                                                     wq1, wq2, wq3, wq4,
                                                     ihw, r1ih, r1hh, r2ih, r2hh,
                                                     wbf, F);
    hmean_kernel<<<dim3(2048), dim3(128), 0, stream>>>(h, F);
    prep_kernel<<<dim3(256), dim3(128), 0, stream>>>(h, ctx2, rec, vtm, la, fa,
                                                     mW1, mb1, mW2, mb2, ihb, iq,
                                                     b1ih, b1hh, b2ih, b2hh,
                                                     F, DESC, out);
    score_kernel<<<dim3(4096), dim3(256), 0, stream>>>(h, wbf, F);
    finalize_kernel<<<dim3(256), dim3(256), 0, stream>>>(F, DESC, vtm, out);
}

// Round 2
// 591.504 us; speedup vs baseline: 1.0793x; 1.0793x over previous
//
#include <hip/hip_runtime.h>
#include <hip/hip_bf16.h>
#include <math.h>

#define GS 1024
#define BSZ 256
#define DD 128
#define NEGV -1e30f

typedef __attribute__((ext_vector_type(8))) short bf16x8_t;
typedef __attribute__((ext_vector_type(4))) float f32x4_t;

// ---- workspace layout (bytes) ----
// [0, 131072)        wbf  : W_K1..4 bf16 [mat][d][k]
// [131072, 524288)   wgru : bf16 [rho][ih/hh][n=384][k=128]
// [524288, 655360)   wqp  : bf16 [rho][n=256][k=128]  (rho0: WQ1|WQ3, rho1: WQ2|WQ4)
// [655360, ...)      F (floats), then DESC (ints)
#define WGRU_OFF_BYTES 131072
#define WQP_OFF_BYTES  524288
#define F_OFF_BYTES    655360
// float offsets inside F:
#define FB_IHWT 0        // 16384   init_hidden_W^T [k][d]
#define FH_HM   16384    // 262144  h-mean partials [b][seg][d]
#define FI_V    278528   // 65536   [b][256] V1|V2
#define FJ_AQB  344064   // 524288  [b][d][j][sel]  sel = {a1,b1,a2,b2}
#define FQ      868352   // 65536   [rho][b][128] GRU hidden
#define FK_RES  933888   // 1048576 [b][g][j]
#define F_TOTAL 1982464
#define DESC_OFF_BYTES (F_OFF_BYTES + F_TOTAL * 4)   // int [b][32]

__device__ __forceinline__ float tanh2(float x) {
    // 1 - 2/(e^{2x}+1); exact saturation at +-inf, no branches
    float e = __expf(x + x);
    return fmaf(-2.0f, __builtin_amdgcn_rcpf(e + 1.0f), 1.0f);
}
__device__ __forceinline__ float sigm2(float x) {
    return __builtin_amdgcn_rcpf(1.0f + __expf(-x));
}
__device__ __forceinline__ unsigned short f2bf(float f) {
    union { float f; unsigned u; } v; v.f = f;
    unsigned u = v.u;
    return (unsigned short)((u + 0x7fffu + ((u >> 16) & 1u)) >> 16);
}
#define MFMA16(a, b, c) __builtin_amdgcn_mfma_f32_16x16x32_bf16((a), (b), (c), 0, 0, 0)

// ---------------- kernel 1: pack weights (all direct-copy bf16 casts) -------
__global__ __launch_bounds__(256) void pack_kernel(
    const float* __restrict__ wk1, const float* __restrict__ wk2,
    const float* __restrict__ wk3, const float* __restrict__ wk4,
    const float* __restrict__ wq1, const float* __restrict__ wq2,
    const float* __restrict__ wq3, const float* __restrict__ wq4,
    const float* __restrict__ ihw,
    const float* __restrict__ r1ih, const float* __restrict__ r1hh,
    const float* __restrict__ r2ih, const float* __restrict__ r2hh,
    unsigned short* __restrict__ wbf, unsigned short* __restrict__ wgru,
    unsigned short* __restrict__ wqp, float* __restrict__ F)
{
    int tid = blockIdx.x * blockDim.x + threadIdx.x;
    int nth = gridDim.x * blockDim.x;
    const float* wks[4]  = {wk1, wk2, wk3, wk4};
    const float* rws[4]  = {r1ih, r1hh, r2ih, r2hh};
    const float* wqs2[4] = {wq1, wq3, wq2, wq4};

    for (int e = tid; e < 65536; e += nth)            // W_K bf16 [mat][d][k]
        wbf[e] = f2bf(wks[e >> 14][e & 16383]);
    for (int e = tid; e < 196608; e += nth) {         // GRU weights, row-major direct
        int part = e / 49152;                         // [rho][ih/hh]
        wgru[e] = f2bf(rws[part][e % 49152]);
    }
    for (int e = tid; e < 65536; e += nth) {          // WQ pairs, row-major direct
        int idx4 = e >> 14;                           // rho*2 + half
        wqp[e] = f2bf(wqs2[idx4][e & 16383]);
    }
    for (int e = tid; e < 16384; e += nth)            // init_hidden_W transposed [k][d]
        F[FB_IHWT + e] = ihw[(e & 127) * 128 + (e >> 7)];
}

// ---------------- kernel 2: h-mean partial sums ----------------
__global__ __launch_bounds__(128) void hmean_kernel(const float* __restrict__ h,
                                                    float* __restrict__ F)
{
    int b = blockIdx.x >> 3, seg = blockIdx.x & 7, d = threadIdx.x;
    const float* base = h + ((size_t)(b * GS + seg * 128)) * DD + d;
    float s = 0.0f;
#pragma unroll 8
    for (int r = 0; r < 128; r++) s += base[(size_t)r * DD];
    F[FH_HM + b * 1024 + seg * 128 + d] = s;
}

// ---------------- kernel 3: per-batch prep (meta, int machine, q0, V) -------
__global__ __launch_bounds__(128) void prepc_kernel(
    const float* __restrict__ ctx2,
    const int* __restrict__ rec, const int* __restrict__ vt,
    const int* __restrict__ la_, const int* __restrict__ fa,
    const float* __restrict__ mW1, const float* __restrict__ mb1,
    const float* __restrict__ mW2, const float* __restrict__ mb2,
    const float* __restrict__ ihb,
    float* __restrict__ F, int* __restrict__ DESC, float* __restrict__ out)
{
    int b = blockIdx.x, tid = threadIdx.x;
    __shared__ float hm[128], hid8[8], c2s[9];

    float s = 0.0f;
#pragma unroll
    for (int seg = 0; seg < 8; seg++) s += F[FH_HM + b * 1024 + seg * 128 + tid];
    hm[tid] = s * (1.0f / 1024.0f);
    if (tid < 9) c2s[tid] = ctx2[b * 9 + tid];

    if (tid == 0) {
        // exact integer state machine (matches jax loop order) — validated R1
        int ai[4], kal[5] = {0, 0, 0, 0, 0}, kar[4] = {0, 0, 0, 0};
        int idesc[26];
        int stopped = 1, nola = -1, vt0 = 0;
        for (int i = 0; i < 4; i++) {
            idesc[16 + i] = stopped;   // stopped at entry of iter i
            idesc[22 + i] = nola;      // nola at entry of iter i
            int action = fa[b * 4 + i];
            if (i > 0 && stopped) action = ai[0];
            int nona = rec[b * GS + action];
            ai[i] = action;
            if (stopped) kal[i] = action;
            int jprev = (i + 3) & 3;
            if (!stopped) kar[jprev] = action;
            kal[i + 1] = nona;
            int hit = (action == nola) ? 1 : 0;
            int st = (i > 0) ? (stopped | hit) : hit;
            if (st) kal[i] = kal[(i + 4) % 5];
            if (st) kar[i] = kar[jprev];
            if (i == 0) vt0 = vt[b * GS + action];
            idesc[0 + i]  = action;
            idesc[4 + i]  = (vt[b * GS + action] - vt0) & (GS - 1);
            idesc[8 + i]  = st;
            idesc[12 + i] = (!st && (nona == ai[0])) ? 1 : 0;
            nola = st ? -1 : nona;
            stopped = st;
        }
        if (!stopped) kar[3] = kal[4];
        idesc[20] = la_[b];
        idesc[21] = vt0;
        int* dd = DESC + b * 32;
        for (int c = 0; c < 26; c++) dd[c] = idesc[c];
        float* oa = out + b * 12;
        for (int c = 0; c < 4; c++) {
            oa[c]     = (float)ai[c];
            oa[4 + c] = (float)kal[c];
            oa[8 + c] = (float)kar[c];
        }
    }
    __syncthreads();

    if (tid < 8) {
        float a = mb1[tid];
        for (int k = 0; k < 9; k++) a += mW1[tid * 9 + k] * c2s[k];
        hid8[tid] = a > 0.0f ? a : 0.0f;
    }
    __syncthreads();
    {   // V1 | V2
        float a = mb2[tid], c = mb2[tid + 128];
        for (int k = 0; k < 8; k++) {
            float hv = hid8[k];
            a += mW2[tid * 8 + k] * hv;
            c += mW2[(tid + 128) * 8 + k] * hv;
        }
        F[FI_V + b * 256 + tid] = a;
        F[FI_V + b * 256 + 128 + tid] = c;
    }
    {   // q0 = IHW @ h_mean + b -> both GRU hidden states
        float q = ihb[tid];
        for (int k = 0; k < 128; k++) q += F[FB_IHWT + k * 128 + tid] * hm[k];
        F[FQ + (0 * 256 + b) * DD + tid] = q;
        F[FQ + (1 * 256 + b) * DD + tid] = q;
    }
}

// ---------------- kernel 4 (x4): one GRU step + AQ projection for all b ----
// grid: 32 blocks = 16 b-tiles(16) x 2 rnns; 256 threads = 4 waves.
// wave w owns output cols [32w, 32w+32) of each gate -> pointwise in-register.
__global__ __launch_bounds__(256) void step_kernel(
    const float* __restrict__ h, float* __restrict__ F,
    const int* __restrict__ DESC,
    const unsigned short* __restrict__ wgru, const unsigned short* __restrict__ wqp,
    const float* __restrict__ b1ih, const float* __restrict__ b1hh,
    const float* __restrict__ b2ih, const float* __restrict__ b2hh,
    const float* __restrict__ iq, int step)
{
    int rho = blockIdx.x & 1;
    int b0  = (blockIdx.x >> 1) * 16;
    int t = threadIdx.x;
    int lane = t & 63, w = t >> 6, ml = lane & 15, quad = lane >> 4;

    __shared__ float Xs[16][132];
    __shared__ float Qs[16][132];
    __shared__ float Qn[16][132];

    const float* bih = rho ? b2ih : b1ih;
    const float* bhh = rho ? b2hh : b1hh;

    // ---- phase 0: stage X (gather) and Q ----
    {
        int row = t >> 4;
        int d0  = (t & 15) * 8;
        int b = b0 + row;
        const float* xsrc;
        if (step == 0) {
            xsrc = iq + d0;
        } else {
            const int* dd = DESC + b * 32;
            int a = dd[step - 1];
            int srcrow;
            if (rho == 0) srcrow = a;
            else {
                int sE = dd[16 + (step - 1)];
                int nl = dd[22 + (step - 1)];
                srcrow = sE ? a : (nl & (GS - 1));
            }
            xsrc = h + ((size_t)(b * GS + srcrow)) * DD + d0;
        }
        const float* qsrc = F + FQ + ((size_t)(rho * 256 + b)) * DD + d0;
#pragma unroll
        for (int e = 0; e < 8; e++) { Xs[row][d0 + e] = xsrc[e]; Qs[row][d0 + e] = qsrc[e]; }
    }
    __syncthreads();

    // ---- phase 1: G_i = X@Wih^T, G_h = Q@Whh^T (kept separate for n-gate) --
    bf16x8_t ax[4], aq[4];
#pragma unroll
    for (int kt = 0; kt < 4; kt++) {
        int k0 = kt * 32 + quad * 8;
        bf16x8_t a, b;
#pragma unroll
        for (int e = 0; e < 8; e++) {
            a[e] = (short)f2bf(Xs[ml][k0 + e]);
            b[e] = (short)f2bf(Qs[ml][k0 + e]);
        }
        ax[kt] = a; aq[kt] = b;
    }
    f32x4_t gi[3][2], gh[3][2];
#pragma unroll
    for (int gate = 0; gate < 3; gate++)
#pragma unroll
        for (int sub = 0; sub < 2; sub++) {
            int n = gate * 128 + w * 32 + sub * 16 + ml;
            const unsigned short* wi = wgru + ((size_t)((rho * 2 + 0) * 384 + n)) * 128 + quad * 8;
            const unsigned short* wh = wgru + ((size_t)((rho * 2 + 1) * 384 + n)) * 128 + quad * 8;
            f32x4_t ai = {0.f, 0.f, 0.f, 0.f}, ah = {0.f, 0.f, 0.f, 0.f};
#pragma unroll
            for (int kt = 0; kt < 4; kt++) {
                bf16x8_t bi = *(const bf16x8_t*)(wi + kt * 32);
                bf16x8_t bh = *(const bf16x8_t*)(wh + kt * 32);
                ai = MFMA16(ax[kt], bi, ai);
                ah = MFMA16(aq[kt], bh, ah);
            }
            gi[gate][sub] = ai; gh[gate][sub] = ah;
        }
    // pointwise GRU update (each lane owns (b=quad*4+r_, d=w*32+sub*16+ml))
#pragma unroll
    for (int sub = 0; sub < 2; sub++) {
        int d = w * 32 + sub * 16 + ml;
        float bir = bih[d], biz = bih[128 + d], bin_ = bih[256 + d];
        float bhr = bhh[d], bhz = bhh[128 + d], bhn = bhh[256 + d];
#pragma unroll
        for (int r_ = 0; r_ < 4; r_++) {
            int brow = quad * 4 + r_;
            float r = sigm2(gi[0][sub][r_] + bir + gh[0][sub][r_] + bhr);
            float z = sigm2(gi[1][sub][r_] + biz + gh[1][sub][r_] + bhz);
            float n = tanh2(gi[2][sub][r_] + bin_ + r * (gh[2][sub][r_] + bhn));
            float qo = Qs[brow][d];
            float qn = fmaf(z, qo - n, n);
            Qn[brow][d] = qn;
            F[FQ + ((size_t)(rho * 256 + b0 + brow)) * DD + d] = qn;
        }
    }
    __syncthreads();

    // ---- phase 2: AQ = q' @ [WQa|WQb]^T for this rnn ----
    bf16x8_t aqn[4];
#pragma unroll
    for (int kt = 0; kt < 4; kt++) {
        int k0 = kt * 32 + quad * 8;
        bf16x8_t a;
#pragma unroll
        for (int e = 0; e < 8; e++) a[e] = (short)f2bf(Qn[ml][k0 + e]);
        aqn[kt] = a;
    }
#pragma unroll
    for (int nt = 0; nt < 4; nt++) {
        int n = w * 64 + nt * 16 + ml;
        const unsigned short* wq = wqp + ((size_t)(rho * 256 + n)) * 128 + quad * 8;
        f32x4_t acc = {0.f, 0.f, 0.f, 0.f};
#pragma unroll
        for (int kt = 0; kt < 4; kt++) {
            bf16x8_t bq = *(const bf16x8_t*)(wq + kt * 32);
            acc = MFMA16(aqn[kt], bq, acc);
        }
        int sel = rho * 2 + (n >> 7);
        int dd2 = n & 127;
#pragma unroll
        for (int r_ = 0; r_ < 4; r_++) {
            int b = b0 + quad * 4 + r_;
            F[FJ_AQB + b * 2048 + dd2 * 16 + step * 4 + sel] = acc[r_];
        }
    }
}

// ---------------- kernel 5: fused MFMA score kernel ----------------
__global__ __launch_bounds__(256) void score_kernel(
    const float* __restrict__ h, const unsigned short* __restrict__ wbf,
    float* __restrict__ F)
{
    int lane = threadIdx.x & 63, w = threadIdx.x >> 6;
    int b  = blockIdx.x >> 4;
    int gt = ((blockIdx.x & 15) << 2) | w;
    int g0 = gt << 4;
    int m = lane & 15, quad = lane >> 4;

    bf16x8_t af[4];
    const float* hrow = h + ((size_t)(b * GS + g0 + m)) * DD + quad * 8;
#pragma unroll
    for (int kt = 0; kt < 4; kt++) {
        f32x4_t f0 = *(const f32x4_t*)(hrow + kt * 32);
        f32x4_t f1 = *(const f32x4_t*)(hrow + kt * 32 + 4);
        bf16x8_t a;
        a[0] = (short)f2bf(f0[0]); a[1] = (short)f2bf(f0[1]);
        a[2] = (short)f2bf(f0[2]); a[3] = (short)f2bf(f0[3]);
        a[4] = (short)f2bf(f1[0]); a[5] = (short)f2bf(f1[1]);
        a[6] = (short)f2bf(f1[2]); a[7] = (short)f2bf(f1[3]);
        af[kt] = a;
    }

    float accp[4][4];
#pragma unroll
    for (int r = 0; r < 4; r++)
#pragma unroll
        for (int j = 0; j < 4; j++) accp[r][j] = 0.0f;

    const float* Vb = F + FI_V + b * 256;
    const float* AQ = F + FJ_AQB + b * 2048;

    for (int nt = 0; nt < 8; nt++) {
        int dg = nt * 16 + m;
        f32x4_t c[4];
#pragma unroll
        for (int mat = 0; mat < 4; mat++) {
            f32x4_t acc = {0.f, 0.f, 0.f, 0.f};
            const unsigned short* wb = wbf + (mat * 128 + dg) * 128 + quad * 8;
#pragma unroll
            for (int kt = 0; kt < 4; kt++) {
                bf16x8_t bfr = *(const bf16x8_t*)(wb + kt * 32);
                acc = MFMA16(af[kt], bfr, acc);
            }
            c[mat] = acc;
        }
        float V1d = Vb[dg], V2d = Vb[128 + dg];
        const f32x4_t* aq4 = (const f32x4_t*)(AQ + dg * 16);
#pragma unroll
        for (int j = 0; j < 4; j++) {
            f32x4_t cj = aq4[j];   // {a1, b1, a2, b2}
#pragma unroll
            for (int r = 0; r < 4; r++) {
                float y1 = c[0][r] + cj[0] + c[2][r] * cj[1];
                float y2 = c[1][r] + cj[2] + c[3][r] * cj[3];
                accp[r][j] = fmaf(tanh2(y1), V1d, fmaf(tanh2(y2), V2d, accp[r][j]));
            }
        }
    }
#pragma unroll
    for (int r = 0; r < 4; r++)
#pragma unroll
        for (int j = 0; j < 4; j++) {
            float v = accp[r][j];
            v += __shfl_xor(v, 1);
            v += __shfl_xor(v, 2);
            v += __shfl_xor(v, 4);
            v += __shfl_xor(v, 8);
            accp[r][j] = v;
        }
    int rr = m >> 2, jj = m & 3;
    float outv = 0.0f;
#pragma unroll
    for (int r = 0; r < 4; r++)
#pragma unroll
        for (int j = 0; j < 4; j++)
            if (rr == r && jj == j) outv = accp[r][j];
    F[FK_RES + ((size_t)(b * GS) + g0 + quad * 4 + rr) * 4 + jj] = outv;
}

// ---------------- kernel 6: masked log-softmax + ll ----------------
__global__ __launch_bounds__(256) void finalize_kernel(
    const float* __restrict__ F, const int* __restrict__ DESC,
    const int* __restrict__ vt, float* __restrict__ out)
{
    int b = blockIdx.x, t = threadIdx.x;
    const int* dd = DESC + b * 32;
    int act0 = dd[0], la = dd[20], vt0 = dd[21];
    __shared__ float sred[8];
    __shared__ float schosen;
    float ll = 0.0f;

    int vtts[4];
#pragma unroll
    for (int q = 0; q < 4; q++) {
        int g = t + q * 256;
        vtts[q] = (vt[b * GS + g] - vt0) & (GS - 1);
    }

    for (int j = 0; j < 4; j++) {
        int aj = dd[j];
        float lg[4];
#pragma unroll
        for (int q = 0; q < 4; q++) {
            int g = t + q * 256;
            bool neg;
            if (j == 0) {
                neg = (g == la);
            } else {
                int p = j - 1;
                neg = (vtts[q] <= dd[4 + p]) || (p == 0 && vtts[q] > GS - 2);
                if (dd[8 + p] && g == dd[p]) neg = false;
                if (dd[12 + p] && g == act0) neg = false;
            }
            float r = F[FK_RES + ((size_t)(b * GS) + g) * 4 + j];
            float v = neg ? NEGV : 6.0f * tanh2(r);
            lg[q] = v;
            if (g == aj) schosen = v;
        }
        float mx = fmaxf(fmaxf(lg[0], lg[1]), fmaxf(lg[2], lg[3]));
#pragma unroll
        for (int o = 1; o < 64; o <<= 1) mx = fmaxf(mx, __shfl_xor(mx, o));
        if ((t & 63) == 0) sred[t >> 6] = mx;
        __syncthreads();
        mx = fmaxf(fmaxf(sred[0], sred[1]), fmaxf(sred[2], sred[3]));
        float sm = 0.0f;
#pragma unroll
        for (int q = 0; q < 4; q++) sm += __expf(lg[q] - mx);
#pragma unroll
        for (int o = 1; o < 64; o <<= 1) sm += __shfl_xor(sm, o);
        if ((t & 63) == 0) sred[4 + (t >> 6)] = sm;
        __syncthreads();
        if (t == 0) {
            float tot = sred[4] + sred[5] + sred[6] + sred[7];
            float lse = mx + logf(tot);
            int gate = (j == 0) || (!dd[16 + j]);
            if (gate) ll += schosen - lse;
        }
        __syncthreads();
    }
    if (t == 0) out[3072 + b] = ll;
}

extern "C" void kernel_launch(void* const* d_in, const int* in_sizes, int n_in,
                              void* d_out, int out_size, void* d_ws, size_t ws_size,
                              hipStream_t stream)
{
    (void)in_sizes; (void)n_in; (void)out_size; (void)ws_size;
    const float* h    = (const float*)d_in[0];
    const float* ctx2 = (const float*)d_in[1];
    const int*   rec  = (const int*)d_in[2];
    const int*   vtm  = (const int*)d_in[3];
    const int*   la   = (const int*)d_in[4];
    const int*   fa   = (const int*)d_in[5];
    const float* wk1 = (const float*)d_in[7];
    const float* wk2 = (const float*)d_in[8];
    const float* wk3 = (const float*)d_in[9];
    const float* wk4 = (const float*)d_in[10];
    const float* wq1 = (const float*)d_in[11];
    const float* wq2 = (const float*)d_in[12];
    const float* wq3 = (const float*)d_in[13];
    const float* wq4 = (const float*)d_in[14];
    const float* mW1 = (const float*)d_in[15];
    const float* mb1 = (const float*)d_in[16];
    const float* mW2 = (const float*)d_in[17];
    const float* mb2 = (const float*)d_in[18];
    const float* ihw = (const float*)d_in[19];
    const float* ihb = (const float*)d_in[20];
    const float* iq  = (const float*)d_in[21];
    const float* r1ih = (const float*)d_in[22];
    const float* r1hh = (const float*)d_in[23];
    const float* b1ih = (const float*)d_in[24];
    const float* b1hh = (const float*)d_in[25];
    const float* r2ih = (const float*)d_in[26];
    const float* r2hh = (const float*)d_in[27];
    const float* b2ih = (const float*)d_in[28];
    const float* b2hh = (const float*)d_in[29];

    unsigned short* wbf  = (unsigned short*)d_ws;
    unsigned short* wgru = (unsigned short*)((char*)d_ws + WGRU_OFF_BYTES);
    unsigned short* wqp  = (unsigned short*)((char*)d_ws + WQP_OFF_BYTES);
    float* F   = (float*)((char*)d_ws + F_OFF_BYTES);
    int* DESC  = (int*)((char*)d_ws + DESC_OFF_BYTES);
    float* out = (float*)d_out;

    pack_kernel<<<dim3(256), dim3(256), 0, stream>>>(wk1, wk2, wk3, wk4,
                                                     wq1, wq2, wq3, wq4,
                                                     ihw, r1ih, r1hh, r2ih, r2hh,
                                                     wbf, wgru, wqp, F);
    hmean_kernel<<<dim3(2048), dim3(128), 0, stream>>>(h, F);
    prepc_kernel<<<dim3(256), dim3(128), 0, stream>>>(ctx2, rec, vtm, la, fa,
                                                      mW1, mb1, mW2, mb2, ihb,
                                                      F, DESC, out);
    for (int i = 0; i < 4; i++)
        step_kernel<<<dim3(32), dim3(256), 0, stream>>>(h, F, DESC, wgru, wqp,
                                                        b1ih, b1hh, b2ih, b2hh,
                                                        iq, i);
    score_kernel<<<dim3(4096), dim3(256), 0, stream>>>(h, wbf, F);
    finalize_kernel<<<dim3(256), dim3(256), 0, stream>>>(F, DESC, vtm, out);
}

// Round 3
// 405.650 us; speedup vs baseline: 1.5738x; 1.4582x over previous
//
#include <hip/hip_runtime.h>
#include <hip/hip_bf16.h>
#include <math.h>

#define GS 1024
#define BSZ 256
#define DD 128
#define NEGV -1e30f

typedef __attribute__((ext_vector_type(8))) short bf16x8_t;
typedef __attribute__((ext_vector_type(4))) float f32x4_t;

// ---- workspace layout (bytes) ----
#define WGRU_OFF_BYTES 131072
#define WQP_OFF_BYTES  524288
#define F_OFF_BYTES    655360
// float offsets inside F:
#define FB_IHWT 0        // 16384   init_hidden_W^T [k][d]
#define FH_HM   16384    // 262144  h-mean partials [b][seg][d]
#define FI_V    278528   // 65536   [b][256] V1|V2
#define FJ_AQB  344064   // 524288  [b][d][j][sel]  sel = {a1,b1,a2,b2} (pre-scaled x2)
#define FQ      868352   // 65536   [rho][b][128] GRU initial hidden
#define FK_RES  933888   // 1048576 [b][j][g]
#define F_TOTAL 1982464
#define DESC_OFF_BYTES (F_OFF_BYTES + F_TOTAL * 4)   // int [b][32]

__device__ __forceinline__ float tanh2(float x) {
    float e = __expf(x + x);
    return fmaf(-2.0f, __builtin_amdgcn_rcpf(e + 1.0f), 1.0f);
}
__device__ __forceinline__ float sigm2(float x) {
    return __builtin_amdgcn_rcpf(1.0f + __expf(-x));
}
__device__ __forceinline__ unsigned short f2bf(float f) {
    union { float f; unsigned u; } v; v.f = f;
    unsigned u = v.u;
    return (unsigned short)((u + 0x7fffu + ((u >> 16) & 1u)) >> 16);
}
#define MFMA16(a, b, c) __builtin_amdgcn_mfma_f32_16x16x32_bf16((a), (b), (c), 0, 0, 0)

// ---------------- kernel 1: pack weights ----------------
// W_K1, W_K2 pre-scaled x2 (additive tanh args); W_K3/4 unscaled (multiplied by x2 AQ b-coeffs)
__global__ __launch_bounds__(256) void pack_kernel(
    const float* __restrict__ wk1, const float* __restrict__ wk2,
    const float* __restrict__ wk3, const float* __restrict__ wk4,
    const float* __restrict__ wq1, const float* __restrict__ wq2,
    const float* __restrict__ wq3, const float* __restrict__ wq4,
    const float* __restrict__ ihw,
    const float* __restrict__ r1ih, const float* __restrict__ r1hh,
    const float* __restrict__ r2ih, const float* __restrict__ r2hh,
    unsigned short* __restrict__ wbf, unsigned short* __restrict__ wgru,
    unsigned short* __restrict__ wqp, float* __restrict__ F)
{
    int tid = blockIdx.x * blockDim.x + threadIdx.x;
    int nth = gridDim.x * blockDim.x;
    const float* wks[4]  = {wk1, wk2, wk3, wk4};
    const float* rws[4]  = {r1ih, r1hh, r2ih, r2hh};
    const float* wqs2[4] = {wq1, wq3, wq2, wq4};

    for (int e = tid; e < 65536; e += nth) {          // W_K bf16 [mat][d][k]
        int mat = e >> 14;
        float s = (mat < 2) ? 2.0f : 1.0f;
        wbf[e] = f2bf(wks[mat][e & 16383] * s);
    }
    for (int e = tid; e < 196608; e += nth) {         // GRU weights row-major
        int part = e / 49152;
        wgru[e] = f2bf(rws[part][e % 49152]);
    }
    for (int e = tid; e < 65536; e += nth)            // WQ pairs row-major
        wqp[e] = f2bf(wqs2[e >> 14][e & 16383]);
    for (int e = tid; e < 16384; e += nth)            // init_hidden_W transposed [k][d]
        F[FB_IHWT + e] = ihw[(e & 127) * 128 + (e >> 7)];
}

// ---------------- kernel 2: h-mean partial sums ----------------
__global__ __launch_bounds__(128) void hmean_kernel(const float* __restrict__ h,
                                                    float* __restrict__ F)
{
    int b = blockIdx.x >> 3, seg = blockIdx.x & 7, d = threadIdx.x;
    const float* base = h + ((size_t)(b * GS + seg * 128)) * DD + d;
    float s = 0.0f;
#pragma unroll 8
    for (int r = 0; r < 128; r++) s += base[(size_t)r * DD];
    F[FH_HM + b * 1024 + seg * 128 + d] = s;
}

// ---------------- kernel 3: per-batch prep (meta, int machine, q0, V) -------
__global__ __launch_bounds__(128) void prepc_kernel(
    const float* __restrict__ ctx2,
    const int* __restrict__ rec, const int* __restrict__ vt,
    const int* __restrict__ la_, const int* __restrict__ fa,
    const float* __restrict__ mW1, const float* __restrict__ mb1,
    const float* __restrict__ mW2, const float* __restrict__ mb2,
    const float* __restrict__ ihb,
    float* __restrict__ F, int* __restrict__ DESC, float* __restrict__ out)
{
    int b = blockIdx.x, tid = threadIdx.x;
    __shared__ float hm[128], hid8[8], c2s[9];

    float s = 0.0f;
#pragma unroll
    for (int seg = 0; seg < 8; seg++) s += F[FH_HM + b * 1024 + seg * 128 + tid];
    hm[tid] = s * (1.0f / 1024.0f);
    if (tid < 9) c2s[tid] = ctx2[b * 9 + tid];

    if (tid == 0) {
        int ai[4], kal[5] = {0, 0, 0, 0, 0}, kar[4] = {0, 0, 0, 0};
        int idesc[26];
        int stopped = 1, nola = -1, vt0 = 0;
        for (int i = 0; i < 4; i++) {
            idesc[16 + i] = stopped;
            idesc[22 + i] = nola;
            int action = fa[b * 4 + i];
            if (i > 0 && stopped) action = ai[0];
            int nona = rec[b * GS + action];
            ai[i] = action;
            if (stopped) kal[i] = action;
            int jprev = (i + 3) & 3;
            if (!stopped) kar[jprev] = action;
            kal[i + 1] = nona;
            int hit = (action == nola) ? 1 : 0;
            int st = (i > 0) ? (stopped | hit) : hit;
            if (st) kal[i] = kal[(i + 4) % 5];
            if (st) kar[i] = kar[jprev];
            if (i == 0) vt0 = vt[b * GS + action];
            idesc[0 + i]  = action;
            idesc[4 + i]  = (vt[b * GS + action] - vt0) & (GS - 1);
            idesc[8 + i]  = st;
            idesc[12 + i] = (!st && (nona == ai[0])) ? 1 : 0;
            nola = st ? -1 : nona;
            stopped = st;
        }
        if (!stopped) kar[3] = kal[4];
        idesc[20] = la_[b];
        idesc[21] = vt0;
        int* dd = DESC + b * 32;
        for (int c = 0; c < 26; c++) dd[c] = idesc[c];
        float* oa = out + b * 12;
        for (int c = 0; c < 4; c++) {
            oa[c]     = (float)ai[c];
            oa[4 + c] = (float)kal[c];
            oa[8 + c] = (float)kar[c];
        }
    }
    __syncthreads();

    if (tid < 8) {
        float a = mb1[tid];
        for (int k = 0; k < 9; k++) a += mW1[tid * 9 + k] * c2s[k];
        hid8[tid] = a > 0.0f ? a : 0.0f;
    }
    __syncthreads();
    {
        float a = mb2[tid], c = mb2[tid + 128];
        for (int k = 0; k < 8; k++) {
            float hv = hid8[k];
            a += mW2[tid * 8 + k] * hv;
            c += mW2[(tid + 128) * 8 + k] * hv;
        }
        F[FI_V + b * 256 + tid] = a;
        F[FI_V + b * 256 + 128 + tid] = c;
    }
    {
        float q = ihb[tid];
        for (int k = 0; k < 128; k++) q += F[FB_IHWT + k * 128 + tid] * hm[k];
        F[FQ + (0 * 256 + b) * DD + tid] = q;
        F[FQ + (1 * 256 + b) * DD + tid] = q;
    }
}

// ---------------- kernel 4: fused 4-step GRU + AQ projection ----------------
// grid 32 = 16 b-tiles x 2 rnns; GRU state LDS-resident across all 4 steps.
__global__ __launch_bounds__(256) void stepf_kernel(
    const float* __restrict__ h, float* __restrict__ F,
    const int* __restrict__ DESC,
    const unsigned short* __restrict__ wgru, const unsigned short* __restrict__ wqp,
    const float* __restrict__ b1ih, const float* __restrict__ b1hh,
    const float* __restrict__ b2ih, const float* __restrict__ b2hh,
    const float* __restrict__ iq)
{
    int rho = blockIdx.x & 1;
    int b0  = (blockIdx.x >> 1) * 16;
    int t = threadIdx.x;
    int lane = t & 63, w = t >> 6, ml = lane & 15, quad = lane >> 4;

    __shared__ float Xs[16][132], Qs[16][132], Qn[16][132];

    const float* bih = rho ? b2ih : b1ih;
    const float* bhh = rho ? b2hh : b1hh;

    int row = t >> 4, d0 = (t & 15) * 8;
    int b = b0 + row;
    const int* dd = DESC + b * 32;

    {   // init Q state
        const float* qsrc = F + FQ + ((size_t)(rho * 256 + b)) * DD + d0;
#pragma unroll
        for (int e = 0; e < 8; e++) Qs[row][d0 + e] = qsrc[e];
    }

    for (int i = 0; i < 4; i++) {
        // ---- gather X for step i (+ commit Q update from step i-1) ----
        {
            if (i > 0) {
#pragma unroll
                for (int e = 0; e < 8; e++) Qs[row][d0 + e] = Qn[row][d0 + e];
            }
            const float* xsrc;
            if (i == 0) xsrc = iq + d0;
            else {
                int a = dd[i - 1];
                int srcrow;
                if (rho == 0) srcrow = a;
                else {
                    int sE = dd[16 + (i - 1)];
                    int nl = dd[22 + (i - 1)];
                    srcrow = sE ? a : (nl & (GS - 1));
                }
                xsrc = h + ((size_t)(b * GS + srcrow)) * DD + d0;
            }
#pragma unroll
            for (int e = 0; e < 8; e++) Xs[row][d0 + e] = xsrc[e];
        }
        __syncthreads();

        // ---- phase 1: gates ----
        bf16x8_t ax[4], aq[4];
#pragma unroll
        for (int kt = 0; kt < 4; kt++) {
            int k0 = kt * 32 + quad * 8;
            bf16x8_t a, bb;
#pragma unroll
            for (int e = 0; e < 8; e++) {
                a[e]  = (short)f2bf(Xs[ml][k0 + e]);
                bb[e] = (short)f2bf(Qs[ml][k0 + e]);
            }
            ax[kt] = a; aq[kt] = bb;
        }
        f32x4_t gi[3][2], gh[3][2];
#pragma unroll
        for (int gate = 0; gate < 3; gate++)
#pragma unroll
            for (int sub = 0; sub < 2; sub++) {
                int n = gate * 128 + w * 32 + sub * 16 + ml;
                const unsigned short* wi = wgru + ((size_t)((rho * 2 + 0) * 384 + n)) * 128 + quad * 8;
                const unsigned short* wh = wgru + ((size_t)((rho * 2 + 1) * 384 + n)) * 128 + quad * 8;
                f32x4_t ai = {0.f, 0.f, 0.f, 0.f}, ah = {0.f, 0.f, 0.f, 0.f};
#pragma unroll
                for (int kt = 0; kt < 4; kt++) {
                    ai = MFMA16(ax[kt], *(const bf16x8_t*)(wi + kt * 32), ai);
                    ah = MFMA16(aq[kt], *(const bf16x8_t*)(wh + kt * 32), ah);
                }
                gi[gate][sub] = ai; gh[gate][sub] = ah;
            }
#pragma unroll
        for (int sub = 0; sub < 2; sub++) {
            int d = w * 32 + sub * 16 + ml;
            float bir = bih[d], biz = bih[128 + d], bin_ = bih[256 + d];
            float bhr = bhh[d], bhz = bhh[128 + d], bhn = bhh[256 + d];
#pragma unroll
            for (int r_ = 0; r_ < 4; r_++) {
                int brow = quad * 4 + r_;
                float r = sigm2(gi[0][sub][r_] + bir + gh[0][sub][r_] + bhr);
                float z = sigm2(gi[1][sub][r_] + biz + gh[1][sub][r_] + bhz);
                float n = tanh2(gi[2][sub][r_] + bin_ + r * (gh[2][sub][r_] + bhn));
                float qo = Qs[brow][d];
                Qn[brow][d] = fmaf(z, qo - n, n);
            }
        }
        __syncthreads();

        // ---- phase 2: AQ = q' @ WQ^T (x2 pre-scale for exp(2x) folding) ----
        bf16x8_t aqn[4];
#pragma unroll
        for (int kt = 0; kt < 4; kt++) {
            int k0 = kt * 32 + quad * 8;
            bf16x8_t a;
#pragma unroll
            for (int e = 0; e < 8; e++) a[e] = (short)f2bf(Qn[ml][k0 + e]);
            aqn[kt] = a;
        }
#pragma unroll
        for (int nt = 0; nt < 4; nt++) {
            int n = w * 64 + nt * 16 + ml;
            const unsigned short* wq = wqp + ((size_t)(rho * 256 + n)) * 128 + quad * 8;
            f32x4_t acc = {0.f, 0.f, 0.f, 0.f};
#pragma unroll
            for (int kt = 0; kt < 4; kt++)
                acc = MFMA16(aqn[kt], *(const bf16x8_t*)(wq + kt * 32), acc);
            int sel = rho * 2 + (n >> 7);
            int dd2 = n & 127;
#pragma unroll
            for (int r_ = 0; r_ < 4; r_++) {
                int b2 = b0 + quad * 4 + r_;
                F[FJ_AQB + b2 * 2048 + dd2 * 16 + i * 4 + sel] = 2.0f * acc[r_];
            }
        }
        __syncthreads();
    }
}

// ---------------- kernel 5: score — d-resident waves, streamed g-tiles ------
// grid 512 = (b, g-half); block 512 thr = 8 waves; wave w owns d-cols [16w,16w+16).
// B/V/AQ in registers for whole kernel; h staged bf16 via dbuf LDS, 1 barrier/iter.
#define SROW 136
__global__ __launch_bounds__(512, 4) void score_kernel(
    const float* __restrict__ h, const unsigned short* __restrict__ wbf,
    float* __restrict__ F)
{
    int b = blockIdx.x >> 1, half = blockIdx.x & 1;
    int t = threadIdx.x;
    int lane = t & 63, w = t >> 6;
    int ml = lane & 15, quad = lane >> 4;
    int dg = w * 16 + ml;

    __shared__ unsigned short stg[2][16 * SROW];
    __shared__ float red[2][64];

    // persistent per-lane preloads (loop-invariant!)
    bf16x8_t bfr[4][4];
#pragma unroll
    for (int mat = 0; mat < 4; mat++)
#pragma unroll
        for (int kt = 0; kt < 4; kt++)
            bfr[mat][kt] = *(const bf16x8_t*)(wbf + ((size_t)(mat * 128 + dg)) * 128 + kt * 32 + quad * 8);
    const float* Vb = F + FI_V + b * 256;
    float V1 = Vb[dg], V2 = Vb[128 + dg];
    float V12 = V1 + V2, n2V1 = -2.0f * V1, n2V2 = -2.0f * V2;
    const float* AQ = F + FJ_AQB + b * 2048 + dg * 16;
    f32x4_t aq4[4];
#pragma unroll
    for (int j = 0; j < 4; j++) aq4[j] = *(const f32x4_t*)(AQ + j * 4);

    int srow = t >> 5;          // 0..15
    int scol = (t & 31) * 4;    // 0..124
    const float* hbase = h + ((size_t)(b * GS + half * 512 + srow)) * DD + scol;

    if (t < 128) red[t >> 6][t & 63] = 0.0f;

    f32x4_t pre = *(const f32x4_t*)hbase;
    {
        unsigned short* dst = &stg[0][srow * SROW + scol];
        dst[0] = f2bf(pre[0]); dst[1] = f2bf(pre[1]);
        dst[2] = f2bf(pre[2]); dst[3] = f2bf(pre[3]);
    }
    __syncthreads();

    for (int tl = 0; tl < 32; tl++) {
        if (tl + 1 < 32)
            pre = *(const f32x4_t*)(hbase + (size_t)(tl + 1) * 16 * DD);

        const unsigned short* sb = stg[tl & 1];
        f32x4_t c[4];
#pragma unroll
        for (int mat = 0; mat < 4; mat++) c[mat] = (f32x4_t){0.f, 0.f, 0.f, 0.f};
#pragma unroll
        for (int kt = 0; kt < 4; kt++) {
            bf16x8_t af = *(const bf16x8_t*)(sb + ml * SROW + kt * 32 + quad * 8);
#pragma unroll
            for (int mat = 0; mat < 4; mat++)
                c[mat] = MFMA16(af, bfr[mat][kt], c[mat]);
        }
        // tanh-combine: v[r*4+j] (C/D: col=ml is d, row=quad*4+r is g)
        float v[16];
#pragma unroll
        for (int j = 0; j < 4; j++) {
            f32x4_t cj = aq4[j];
#pragma unroll
            for (int r = 0; r < 4; r++) {
                float y1 = fmaf(c[2][r], cj[1], c[0][r] + cj[0]);
                float y2 = fmaf(c[3][r], cj[3], c[1][r] + cj[2]);
                float r1 = __builtin_amdgcn_rcpf(__expf(y1) + 1.0f);
                float r2 = __builtin_amdgcn_rcpf(__expf(y2) + 1.0f);
                v[r * 4 + j] = fmaf(n2V1, r1, fmaf(n2V2, r2, V12));
            }
        }
        // butterfly reduce over the quad's 16 lanes: lane ml ends with sum of v[ml]
        {
            int bs = ml & 1;
#pragma unroll
            for (int i = 0; i < 8; i++) {
                float lo = v[2 * i], hi = v[2 * i + 1];
                float send = bs ? lo : hi;
                float recv = __shfl_xor(send, 1);
                v[i] = (bs ? hi : lo) + recv;
            }
        }
        {
            int bs = (ml >> 1) & 1;
#pragma unroll
            for (int i = 0; i < 4; i++) {
                float lo = v[2 * i], hi = v[2 * i + 1];
                float send = bs ? lo : hi;
                float recv = __shfl_xor(send, 2);
                v[i] = (bs ? hi : lo) + recv;
            }
        }
        {
            int bs = (ml >> 2) & 1;
#pragma unroll
            for (int i = 0; i < 2; i++) {
                float lo = v[2 * i], hi = v[2 * i + 1];
                float send = bs ? lo : hi;
                float recv = __shfl_xor(send, 4);
                v[i] = (bs ? hi : lo) + recv;
            }
        }
        {
            int bs = (ml >> 3) & 1;
            float lo = v[0], hi = v[1];
            float send = bs ? lo : hi;
            float recv = __shfl_xor(send, 8);
            v[0] = (bs ? hi : lo) + recv;
        }
        atomicAdd(&red[tl & 1][quad * 16 + ml], v[0]);

        if (tl + 1 < 32) {
            unsigned short* dst = &stg[(tl + 1) & 1][srow * SROW + scol];
            dst[0] = f2bf(pre[0]); dst[1] = f2bf(pre[1]);
            dst[2] = f2bf(pre[2]); dst[3] = f2bf(pre[3]);
        }
        __syncthreads();
        if (t < 64) {
            int j = t >> 4, gp = t & 15;
            int ridx = (gp >> 2) * 16 + (gp & 3) * 4 + j;
            float val = red[tl & 1][ridx];
            red[tl & 1][ridx] = 0.0f;
            int g = half * 512 + tl * 16 + gp;
            F[FK_RES + (size_t)b * 4096 + j * 1024 + g] = val;
        }
        // no barrier needed: next iter touches red[(tl+1)&1] / stg[(tl)&1... disjoint];
        // reset of red[tl&1] is separated from its next use (tl+2) by the tl+1 barrier.
    }
}

// ---------------- kernel 6: masked log-softmax + ll ----------------
__global__ __launch_bounds__(256) void finalize_kernel(
    const float* __restrict__ F, const int* __restrict__ DESC,
    const int* __restrict__ vt, float* __restrict__ out)
{
    int b = blockIdx.x, t = threadIdx.x;
    const int* dd = DESC + b * 32;
    int act0 = dd[0], la = dd[20], vt0 = dd[21];
    __shared__ float sred[8];
    __shared__ float schosen;
    float ll = 0.0f;

    int vtts[4];
#pragma unroll
    for (int q = 0; q < 4; q++) {
        int g = t + q * 256;
        vtts[q] = (vt[b * GS + g] - vt0) & (GS - 1);
    }

    for (int j = 0; j < 4; j++) {
        int aj = dd[j];
        float lg[4];
#pragma unroll
        for (int q = 0; q < 4; q++) {
            int g = t + q * 256;
            bool neg;
            if (j == 0) {
                neg = (g == la);
            } else {
                int p = j - 1;
                neg = (vtts[q] <= dd[4 + p]) || (p == 0 && vtts[q] > GS - 2);
                if (dd[8 + p] && g == dd[p]) neg = false;
                if (dd[12 + p] && g == act0) neg = false;
            }
            float r = F[FK_RES + (size_t)b * 4096 + j * 1024 + g];
            float vv = neg ? NEGV : 6.0f * tanh2(r);
            lg[q] = vv;
            if (g == aj) schosen = vv;
        }
        float mx = fmaxf(fmaxf(lg[0], lg[1]), fmaxf(lg[2], lg[3]));
#pragma unroll
        for (int o = 1; o < 64; o <<= 1) mx = fmaxf(mx, __shfl_xor(mx, o));
        if ((t & 63) == 0) sred[t >> 6] = mx;
        __syncthreads();
        mx = fmaxf(fmaxf(sred[0], sred[1]), fmaxf(sred[2], sred[3]));
        float sm = 0.0f;
#pragma unroll
        for (int q = 0; q < 4; q++) sm += __expf(lg[q] - mx);
#pragma unroll
        for (int o = 1; o < 64; o <<= 1) sm += __shfl_xor(sm, o);
        if ((t & 63) == 0) sred[4 + (t >> 6)] = sm;
        __syncthreads();
        if (t == 0) {
            float tot = sred[4] + sred[5] + sred[6] + sred[7];
            float lse = mx + logf(tot);
            int gate = (j == 0) || (!dd[16 + j]);
            if (gate) ll += schosen - lse;
        }
        __syncthreads();
    }
    if (t == 0) out[3072 + b] = ll;
}

extern "C" void kernel_launch(void* const* d_in, const int* in_sizes, int n_in,
                              void* d_out, int out_size, void* d_ws, size_t ws_size,
                              hipStream_t stream)
{
    (void)in_sizes; (void)n_in; (void)out_size; (void)ws_size;
    const float* h    = (const float*)d_in[0];
    const float* ctx2 = (const float*)d_in[1];
    const int*   rec  = (const int*)d_in[2];
    const int*   vtm  = (const int*)d_in[3];
    const int*   la   = (const int*)d_in[4];
    const int*   fa   = (const int*)d_in[5];
    const float* wk1 = (const float*)d_in[7];
    const float* wk2 = (const float*)d_in[8];
    const float* wk3 = (const float*)d_in[9];
    const float* wk4 = (const float*)d_in[10];
    const float* wq1 = (const float*)d_in[11];
    const float* wq2 = (const float*)d_in[12];
    const float* wq3 = (const float*)d_in[13];
    const float* wq4 = (const float*)d_in[14];
    const float* mW1 = (const float*)d_in[15];
    const float* mb1 = (const float*)d_in[16];
    const float* mW2 = (const float*)d_in[17];
    const float* mb2 = (const float*)d_in[18];
    const float* ihw = (const float*)d_in[19];
    const float* ihb = (const float*)d_in[20];
    const float* iq  = (const float*)d_in[21];
    const float* r1ih = (const float*)d_in[22];
    const float* r1hh = (const float*)d_in[23];
    const float* b1ih = (const float*)d_in[24];
    const float* b1hh = (const float*)d_in[25];
    const float* r2ih = (const float*)d_in[26];
    const float* r2hh = (const float*)d_in[27];
    const float* b2ih = (const float*)d_in[28];
    const float* b2hh = (const float*)d_in[29];

    unsigned short* wbf  = (unsigned short*)d_ws;
    unsigned short* wgru = (unsigned short*)((char*)d_ws + WGRU_OFF_BYTES);
    unsigned short* wqp  = (unsigned short*)((char*)d_ws + WQP_OFF_BYTES);
    float* F   = (float*)((char*)d_ws + F_OFF_BYTES);
    int* DESC  = (int*)((char*)d_ws + DESC_OFF_BYTES);
    float* out = (float*)d_out;

    pack_kernel<<<dim3(256), dim3(256), 0, stream>>>(wk1, wk2, wk3, wk4,
                                                     wq1, wq2, wq3, wq4,
                                                     ihw, r1ih, r1hh, r2ih, r2hh,
                                                     wbf, wgru, wqp, F);
    hmean_kernel<<<dim3(2048), dim3(128), 0, stream>>>(h, F);
    prepc_kernel<<<dim3(256), dim3(128), 0, stream>>>(ctx2, rec, vtm, la, fa,
                                                      mW1, mb1, mW2, mb2, ihb,
                                                      F, DESC, out);
    stepf_kernel<<<dim3(32), dim3(256), 0, stream>>>(h, F, DESC, wgru, wqp,
                                                     b1ih, b1hh, b2ih, b2hh, iq);
    score_kernel<<<dim3(512), dim3(512), 0, stream>>>(h, wbf, F);
    finalize_kernel<<<dim3(256), dim3(256), 0, stream>>>(F, DESC, vtm, out);
}